// Round 4
// baseline (644.342 us; speedup 1.0000x reference)
//
#include <hip/hip_runtime.h>
#include <hip/hip_bf16.h>
#include <math.h>
#include <stdint.h>

#define B_    32
#define S_    512
#define H_    768
#define NH_   12
#define HD_   64
#define NCOL_ 32
#define M_    (B_*S_)   // 16384

typedef __bf16 bf16;
typedef __bf16 bf16x8 __attribute__((ext_vector_type(8)));
typedef __bf16 bf16x4 __attribute__((ext_vector_type(4)));
typedef float  f32x4  __attribute__((ext_vector_type(4)));

// ---------------------------------------------------------------------------
// async global->LDS 16B copy (global_load_lds_dwordx4)
// ---------------------------------------------------------------------------
__device__ __forceinline__ void async_load16(const void* g, void* l) {
    __builtin_amdgcn_global_load_lds(
        (__attribute__((address_space(1))) unsigned int*)g,
        (__attribute__((address_space(3))) unsigned int*)l, 16, 0, 0);
}

// fp32 -> bf16x8 converting load (32B in)
__device__ __forceinline__ bf16x8 cvt8(const float* p) {
    const float4* fp = (const float4*)p;
    float4 x = fp[0], y = fp[1];
    bf16x8 r;
    r[0] = (bf16)x.x; r[1] = (bf16)x.y; r[2] = (bf16)x.z; r[3] = (bf16)x.w;
    r[4] = (bf16)y.x; r[5] = (bf16)y.y; r[6] = (bf16)y.z; r[7] = (bf16)y.w;
    return r;
}

// ---------------------------------------------------------------------------
// fused convert: hidden->hbf, gather->hcol, weights->wpack, qkv bias pack
// ---------------------------------------------------------------------------
__global__ __launch_bounds__(256) void cvt_kernel(
    const float* __restrict__ hidden, const float* __restrict__ ce,
    const int* __restrict__ cc, const int* __restrict__ vm,
    const float* __restrict__ Wd, const float* __restrict__ Wc,
    const float* __restrict__ Wq, const float* __restrict__ Wk,
    const float* __restrict__ Wv, const float* __restrict__ Wo,
    const float* __restrict__ bq, const float* __restrict__ bk,
    const float* __restrict__ bv,
    bf16* __restrict__ hbf, bf16* __restrict__ hcol,
    bf16* __restrict__ wpack, float* __restrict__ bqkv)
{
    int blk = blockIdx.x;
    if (blk < 6144) {
        int id = blk * 256 + threadIdx.x;
        int row = id / 96, c = id - row * 96;
        *(bf16x8*)&hbf[(long)row * H_ + c * 8] = cvt8(hidden + (long)row * H_ + c * 8);
    } else if (blk < 12288) {
        int id = (blk - 6144) * 256 + threadIdx.x;
        int row = id / 96, c = id - row * 96;
        int b = row >> 9;
        int m = vm[row];
        bf16x8 val;
#pragma unroll
        for (int i = 0; i < 8; i++) val[i] = (bf16)0.0f;
        if (m > 0) {
            int col = m - 1;
            if (cc[b * NCOL_ + col] == 1)
                val = cvt8(ce + ((long)(b * NCOL_ + col)) * H_ + c * 8);
        }
        *(bf16x8*)&hcol[(long)row * H_ + c * 8] = val;
    } else {
        int id = (blk - 12288) * 256 + threadIdx.x;
        if (id < 442368) {
            const float* src;
            int r = id;
            if      (r < 73728)  { src = Wd; }
            else if (r < 147456) { src = Wc; r -= 73728; }
            else if (r < 221184) { src = Wq; r -= 147456; }
            else if (r < 294912) { src = Wk; r -= 221184; }
            else if (r < 368640) { src = Wv; r -= 294912; }
            else                 { src = Wo; r -= 368640; }
            *(bf16x8*)&wpack[(long)id * 8] = cvt8(src + (long)r * 8);
        } else if (id < 442656) {
            int j0 = (id - 442368) * 8;
#pragma unroll
            for (int i = 0; i < 8; i++) {
                int j = j0 + i;
                float v = (j < 768) ? bq[j] : (j < 1536) ? bk[j - 768] : bv[j - 1536];
                bqkv[j] = v;
            }
        }
    }
}

// ---------------------------------------------------------------------------
// GEMM C[m,n] = sum_k A[m,k]*Bw[n,k]  (+ epilogue per MODE), bf16, lda=ldb=768
//
// BM=256 BN=128 BK=32, 512 threads = 8 waves (4x2 bands, 64x64/wave).
// TRIPLE-buffered LDS, 72KB -> 2 blocks/CU. Counted vmcnt(3): stage(t+2)
// issued in iter t, drains at end of iter t+1. ONE barrier per K-tile.
// 2-bit XOR chunk swizzle via pre-swizzled global source + swizzled ds_read.
//
// Round 3 (re-submitted after infra failure): software-pipelined FRAGMENT
// reads — after MFMA(t) and the counted vmcnt (which guarantees tile t+1's
// LDS data landed), the frag ds_reads for tile t+1 are issued BEFORE the
// end-of-tile barrier, so their ~120cy LDS latency completes in the
// barrier-wait shadow and MFMAs fire immediately at tile start. Two
// static-named frag sets alternate roles via a 2x-unrolled loop (no runtime
// indexing -> stays in registers, rule #20); cur set dies exactly where next
// set is born, so peak VGPR ~unchanged. Race-free: reads hit buffer (t+1)%3,
// concurrent stages write (t+2)%3.
//
// MODE 0: gelu(acc + bias1 + bias2) -> [M,768] bf16
// MODE 1: acc + bias1 -> qkv: Q,K sections [B,NH,S,HD]; V section [B,NH,HD,S]
// MODE 2: acc + bias1 + resid -> [M,768] bf16 (in-place ok)
// ---------------------------------------------------------------------------
template<int MODE>
__global__ __launch_bounds__(512, 4) void gemm_bt(
    const bf16* __restrict__ A0, const bf16* __restrict__ A1,
    const bf16* __restrict__ B0, const bf16* __restrict__ B1,
    const float* __restrict__ bias1, const float* __restrict__ bias2,
    const bf16* __restrict__ resid, bf16* __restrict__ out,
    int K, int KSPLIT)
{
    __shared__ __align__(16) bf16 SA[3][256 * 32];   // 3 x 16KB
    __shared__ __align__(16) bf16 SB[3][128 * 32];   // 3 x  8KB

    const int tid  = threadIdx.x;
    const int lane = tid & 63;
    const int wave = tid >> 6;
    const int wr   = wave >> 1;          // 0..3: 64-row band of A
    const int wc   = wave & 1;           // 0..1: 64-col band of B
    const int quad = lane >> 4;
    const int ln16 = lane & 15;
    const int m0   = blockIdx.x * 256;
    const int n0   = blockIdx.y * 128;

    // staging geometry: 16B chunks, 4 chunks per 32-elem row. Physical chunk
    // p in row r holds LOGICAL chunk p ^ ((r>>1)&3) -> pre-swizzle the global
    // source column so the LDS dest stays linear (global_load_lds constraint).
    int arow[2], acol[2];
#pragma unroll
    for (int q = 0; q < 2; q++) {
        int l = q * 512 + tid;
        int row = l >> 2;
        arow[q] = row;
        acol[q] = ((l & 3) ^ ((row >> 1) & 3)) * 8;
    }
    const int brow = tid >> 2;
    const int bcol = ((tid & 3) ^ ((brow >> 1) & 3)) * 8;

    auto stage = [&](int kt, int bsel) {
        int kk = kt * 32;
        const bf16* ag = (kk < KSPLIT) ? A0 + kk : A1 + (kk - KSPLIT);
        const bf16* bg = (kk < KSPLIT) ? B0 + kk : B1 + (kk - KSPLIT);
        async_load16(ag + (long)(m0 + arow[0]) * H_ + acol[0], &SA[bsel][tid * 8]);
        async_load16(ag + (long)(m0 + arow[1]) * H_ + acol[1], &SA[bsel][4096 + tid * 8]);
        async_load16(bg + (long)(n0 + brow)    * H_ + bcol,    &SB[bsel][tid * 8]);
    };

    f32x4 acc[4][4];
    const f32x4 zero4 = {0.f, 0.f, 0.f, 0.f};
#pragma unroll
    for (int i = 0; i < 4; i++)
#pragma unroll
        for (int j = 0; j < 4; j++) acc[i][j] = zero4;

    // fragment LDS offsets (swizzled read side)
    const int s4 = (ln16 >> 1) & 3;
    int aoff[4], boff[4];
#pragma unroll
    for (int i = 0; i < 4; i++) {
        aoff[i] = (wr * 64 + i * 16 + ln16) * 32 + (quad ^ s4) * 8;
        boff[i] = (wc * 64 + i * 16 + ln16) * 32 + (quad ^ s4) * 8;
    }

    const int nt = K >> 5;               // 24 or 48 K-tiles (always even)

    // ---- prologue: tiles 0,1 -> buffers 0,1; wait tile 0 (3 loads in flight)
    stage(0, 0);
    stage(1, 1);
    asm volatile("s_waitcnt vmcnt(3)" ::: "memory");
    __builtin_amdgcn_sched_barrier(0);
    __builtin_amdgcn_s_barrier();

    bf16x8 afA[4], bfA[4], afB[4], bfB[4];
#pragma unroll
    for (int i = 0; i < 4; i++) afA[i] = *(const bf16x8*)&SA[0][aoff[i]];
#pragma unroll
    for (int j = 0; j < 4; j++) bfA[j] = *(const bf16x8*)&SB[0][boff[j]];

    int bs = 0;
    auto iter = [&](int t, bf16x8 (&fa)[4], bf16x8 (&fb)[4],
                    bf16x8 (&na)[4], bf16x8 (&nb)[4]) {
        const int ps = (bs + 2 >= 3) ? bs - 1 : bs + 2;   // (t+2)%3
        if (t + 2 < nt) stage(t + 2, ps);

        __builtin_amdgcn_s_setprio(1);
#pragma unroll
        for (int i = 0; i < 4; i++)
#pragma unroll
            for (int j = 0; j < 4; j++)
                acc[i][j] = __builtin_amdgcn_mfma_f32_16x16x32_bf16(fa[i], fb[j], acc[i][j], 0, 0, 0);
        __builtin_amdgcn_s_setprio(0);

        if (t + 1 < nt) {
            // tile t+1's 3 loads are the oldest outstanding: counted wait
            // drains exactly them (t+2's 3, issued this iter, stay in flight).
            if (t + 2 < nt) { asm volatile("s_waitcnt vmcnt(3)" ::: "memory"); }
            else            { asm volatile("s_waitcnt vmcnt(0)" ::: "memory"); }
            const int nbuf = (bs + 1 == 3) ? 0 : bs + 1;
            // frag reads for t+1 BEFORE the barrier: latency hides under
            // barrier wait. Reads buffer (t+1)%3; concurrent stage writes go
            // to (t+2)%3 — disjoint.
#pragma unroll
            for (int i = 0; i < 4; i++) na[i] = *(const bf16x8*)&SA[nbuf][aoff[i]];
#pragma unroll
            for (int j = 0; j < 4; j++) nb[j] = *(const bf16x8*)&SB[nbuf][boff[j]];
            __builtin_amdgcn_sched_barrier(0);
            __builtin_amdgcn_s_barrier();
        }
        bs = (bs + 1 == 3) ? 0 : bs + 1;
    };

    for (int t = 0; t < nt; t += 2) {
        iter(t,     afA, bfA, afB, bfB);
        iter(t + 1, afB, bfB, afA, bfA);
    }

    // ---- epilogue (identical mapping to verified round-2 kernel)
    const int c_r = quad * 4;
    const int c_c = ln16;

    int sec = 0;
    if (MODE == 1) sec = (n0 >= 1536) ? 2 : ((n0 >= 768) ? 1 : 0);
    bf16* dst = (MODE == 1) ? out + (long)sec * M_ * H_ : out;

#pragma unroll
    for (int j = 0; j < 4; j++) {
        const int col = n0 + wc * 64 + j * 16 + c_c;
        float bias = bias1[col];
        if (MODE == 0) bias += bias2[col];
#pragma unroll
        for (int i = 0; i < 4; i++) {
            if (MODE == 1 && sec == 2) {
                // V transposed [B,NH,HD,S]: 4 consecutive s -> one 8B store
                const int row0 = m0 + wr * 64 + i * 16 + c_r;   // 4-aligned
                int b = row0 >> 9, s = row0 & 511;
                int cs = col - 1536;
                int head = cs >> 6, d = cs & 63;
                bf16x4 pk;
#pragma unroll
                for (int r = 0; r < 4; r++) pk[r] = (bf16)(acc[i][j][r] + bias);
                *(bf16x4*)&dst[(((long)(b * NH_ + head)) * HD_ + d) * S_ + s] = pk;
            } else {
#pragma unroll
                for (int r = 0; r < 4; r++) {
                    const int row = m0 + wr * 64 + i * 16 + c_r + r;
                    float v = acc[i][j][r] + bias;
                    if (MODE == 0) {
                        v = 0.5f * v * (1.0f + erff(v * 0.70710678118654752f));
                        dst[(long)row * H_ + col] = (bf16)v;
                    } else if (MODE == 1) {
                        int b = row >> 9, s = row & 511;
                        int cs = col - sec * 768;
                        int head = cs >> 6, d = cs & 63;
                        dst[(((long)(b * NH_ + head)) * S_ + s) * HD_ + d] = (bf16)v;
                    } else {
                        v += (float)resid[(long)row * H_ + col];
                        dst[(long)row * H_ + col] = (bf16)v;
                    }
                }
            }
        }
    }
}

// ---------------------------------------------------------------------------
// flash attention, transposed-score form (unchanged).
// ---------------------------------------------------------------------------
#define QP 72   // LDS row stride (elems): 144 B, 16B-aligned

__global__ __launch_bounds__(256) void attn_kernel(
    const bf16* __restrict__ q, const bf16* __restrict__ k,
    const bf16* __restrict__ vt, bf16* __restrict__ ctx)
{
    __shared__ __align__(16) bf16 Qs[64 * QP];
    __shared__ __align__(16) bf16 Ks[64 * QP];
    __shared__ __align__(16) bf16 Vt[64 * QP];      // V^T chunk: [d][t]
    __shared__ __align__(16) bf16 Ps[4][16 * QP];   // per-wave P: [q][t]

    const int tid  = threadIdx.x;
    const int lane = tid & 63;
    const int w    = tid >> 6;
    const int quad = lane >> 4;
    const int ln16 = lane & 15;

    const int bid = blockIdx.x;
    const int qt  = bid / 384;          // qt-major: same g -> same XCD (384%8==0)
    const int g   = bid - qt * 384;
    const int b   = g / 12;
    const int h   = g - b * 12;
    const long base = ((long)(b * NH_ + h)) * S_ * HD_;

    const int r0 = tid >> 2;            // row 0..63
    const int e0 = (tid & 3) * 16;      // col elems 0,16,32,48

    {
        const bf16* qg = q + base + (long)qt * 64 * HD_;
        *(uint4*)&Qs[r0 * QP + e0]     = *(const uint4*)&qg[r0 * HD_ + e0];
        *(uint4*)&Qs[r0 * QP + e0 + 8] = *(const uint4*)&qg[r0 * HD_ + e0 + 8];
    }
    const bf16* kg = k  + base;
    const bf16* vg = vt + base;
    uint4 kr0 = *(const uint4*)&kg[r0 * HD_ + e0];
    uint4 kr1 = *(const uint4*)&kg[r0 * HD_ + e0 + 8];
    uint4 vr0 = *(const uint4*)&vg[(long)r0 * S_ + e0];
    uint4 vr1 = *(const uint4*)&vg[(long)r0 * S_ + e0 + 8];
    __syncthreads();

    const bf16x8 bq0 = *(const bf16x8*)&Qs[(w * 16 + ln16) * QP + quad * 8];
    const bf16x8 bq1 = *(const bf16x8*)&Qs[(w * 16 + ln16) * QP + 32 + quad * 8];

    f32x4 O[4];
    const f32x4 zero4 = {0.f, 0.f, 0.f, 0.f};
#pragma unroll
    for (int t = 0; t < 4; t++) O[t] = zero4;
    float mo = -1e30f, l = 0.f;

    for (int kc = 0; kc < 8; kc++) {
        __syncthreads();
        *(uint4*)&Ks[r0 * QP + e0]     = kr0;
        *(uint4*)&Ks[r0 * QP + e0 + 8] = kr1;
        *(uint4*)&Vt[r0 * QP + e0]     = vr0;
        *(uint4*)&Vt[r0 * QP + e0 + 8] = vr1;
        {
            int kcn = (kc < 7) ? kc + 1 : 7;
            kr0 = *(const uint4*)&kg[(long)kcn * 64 * HD_ + r0 * HD_ + e0];
            kr1 = *(const uint4*)&kg[(long)kcn * 64 * HD_ + r0 * HD_ + e0 + 8];
            vr0 = *(const uint4*)&vg[(long)r0 * S_ + kcn * 64 + e0];
            vr1 = *(const uint4*)&vg[(long)r0 * S_ + kcn * 64 + e0 + 8];
        }
        __syncthreads();

        f32x4 sc[4];
#pragma unroll
        for (int i = 0; i < 4; i++) {
            bf16x8 a0 = *(const bf16x8*)&Ks[(i * 16 + ln16) * QP + quad * 8];
            bf16x8 a1 = *(const bf16x8*)&Ks[(i * 16 + ln16) * QP + 32 + quad * 8];
            sc[i] = zero4;
            sc[i] = __builtin_amdgcn_mfma_f32_16x16x32_bf16(a0, bq0, sc[i], 0, 0, 0);
            sc[i] = __builtin_amdgcn_mfma_f32_16x16x32_bf16(a1, bq1, sc[i], 0, 0, 0);
        }

        float cm = -1e30f;
#pragma unroll
        for (int i = 0; i < 4; i++)
#pragma unroll
            for (int r = 0; r < 4; r++) {
                float s = sc[i][r] * 0.125f;
                sc[i][r] = s;
                cm = fmaxf(cm, s);
            }
        cm = fmaxf(cm, __shfl_xor(cm, 16));
        cm = fmaxf(cm, __shfl_xor(cm, 32));
        float mn = fmaxf(mo, cm);
        float alpha = __expf(mo - mn);
        float rs = 0.f;
#pragma unroll
        for (int i = 0; i < 4; i++) {
            bf16x4 pk;
#pragma unroll
            for (int r = 0; r < 4; r++) {
                float p = __expf(sc[i][r] - mn);
                rs += p;
                pk[r] = (bf16)p;
            }
            *(bf16x4*)&Ps[w][ln16 * QP + i * 16 + quad * 4] = pk;
        }
        rs += __shfl_xor(rs, 16);
        rs += __shfl_xor(rs, 32);
        l  = l * alpha + rs;
        mo = mn;
#pragma unroll
        for (int t = 0; t < 4; t++)
#pragma unroll
            for (int r = 0; r < 4; r++) O[t][r] *= alpha;

        bf16x8 bp0 = *(const bf16x8*)&Ps[w][ln16 * QP + quad * 8];
        bf16x8 bp1 = *(const bf16x8*)&Ps[w][ln16 * QP + 32 + quad * 8];
#pragma unroll
        for (int dt = 0; dt < 4; dt++) {
            bf16x8 a0 = *(const bf16x8*)&Vt[(dt * 16 + ln16) * QP + quad * 8];
            bf16x8 a1 = *(const bf16x8*)&Vt[(dt * 16 + ln16) * QP + 32 + quad * 8];
            O[dt] = __builtin_amdgcn_mfma_f32_16x16x32_bf16(a0, bp0, O[dt], 0, 0, 0);
            O[dt] = __builtin_amdgcn_mfma_f32_16x16x32_bf16(a1, bp1, O[dt], 0, 0, 0);
        }
    }

    {
        float inv = 1.0f / l;
#pragma unroll
        for (int dt = 0; dt < 4; dt++) {
            bf16x4 ov;
#pragma unroll
            for (int r = 0; r < 4; r++) ov[r] = (bf16)(O[dt][r] * inv);
            *(bf16x4*)&Qs[(w * 16 + ln16) * QP + dt * 16 + quad * 4] = ov;
        }
    }
    __syncthreads();
    {
        uint4 o0 = *(const uint4*)&Qs[r0 * QP + e0];
        uint4 o1 = *(const uint4*)&Qs[r0 * QP + e0 + 8];
        bf16* cg = ctx + ((long)(b * S_ + qt * 64 + r0)) * H_ + h * HD_;
        *(uint4*)&cg[e0]     = o0;
        *(uint4*)&cg[e0 + 8] = o1;
    }
}

// ---------------------------------------------------------------------------
// layernorm: one wave per row; bf16 in, fp32 out
// ---------------------------------------------------------------------------
__global__ __launch_bounds__(256) void ln_kernel(
    const bf16* __restrict__ y, const float* __restrict__ g,
    const float* __restrict__ be, float* __restrict__ out)
{
    const int lane = threadIdx.x & 63;
    const int w    = threadIdx.x >> 6;
    const long row = (long)blockIdx.x * 4 + w;
    const bf16* yr = y + row * H_;

    float x[12];
    float sum = 0.f, ss = 0.f;
#pragma unroll
    for (int j = 0; j < 12; j++) {
        x[j] = (float)yr[j * 64 + lane];
        sum += x[j];
        ss  += x[j] * x[j];
    }
#pragma unroll
    for (int m = 1; m < 64; m <<= 1) {
        sum += __shfl_xor(sum, m);
        ss  += __shfl_xor(ss, m);
    }
    const float mu  = sum * (1.0f / 768.0f);
    float var = ss * (1.0f / 768.0f) - mu * mu;
    const float rs = rsqrtf(fmaxf(var, 0.f) + 1e-12f);
#pragma unroll
    for (int j = 0; j < 12; j++) {
        int c = j * 64 + lane;
        out[row * H_ + c] = (x[j] - mu) * rs * g[c] + be[c];
    }
}

// ---------------------------------------------------------------------------
extern "C" void kernel_launch(void* const* d_in, const int* in_sizes, int n_in,
                              void* d_out, int out_size, void* d_ws, size_t ws_size,
                              hipStream_t stream)
{
    const float* hidden = (const float*)d_in[0];
    const float* ce     = (const float*)d_in[1];
    const int*   cc     = (const int*)d_in[2];
    const int*   vm     = (const int*)d_in[3];
    const float* Wd     = (const float*)d_in[4];
    const float* bd     = (const float*)d_in[5];
    const float* Wc     = (const float*)d_in[6];
    const float* bc     = (const float*)d_in[7];
    const float* Wq     = (const float*)d_in[8];
    const float* bq     = (const float*)d_in[9];
    const float* Wk     = (const float*)d_in[10];
    const float* bk     = (const float*)d_in[11];
    const float* Wv     = (const float*)d_in[12];
    const float* bv     = (const float*)d_in[13];
    const float* Wo     = (const float*)d_in[14];
    const float* bo     = (const float*)d_in[15];
    const float* lng    = (const float*)d_in[16];
    const float* lnb    = (const float*)d_in[17];

    // ---- workspace layout (bf16 elems; total ~102.8 MB) ----
    const long NE = (long)M_ * H_;
    bf16* ws   = (bf16*)d_ws;
    bf16* hbuf = ws;                          // gelu out / resid / y
    bf16* qkv  = ws + NE;                     // qb,kb,vb contiguous
    bf16* hbf  = qkv;                         // hbf over qb (dead before QKV writes)
    bf16* hcol = qkv + NE;                    // hcol over kb
    bf16* qb   = qkv;
    bf16* kb   = qkv + NE;
    bf16* vb   = qkv + 2 * NE;                // V^T layout [B,NH,HD,S]
    bf16* wpack = ws + 4 * NE;
    const bf16* Wd_b  = wpack;
    const bf16* Wc_b  = wpack + 589824;
    const bf16* Wq_b  = wpack + 1179648;
    const bf16* Wk_b  = wpack + 1769472;
    const bf16* Wv_b  = wpack + 2359296;
    const bf16* Wo_b  = wpack + 2949120;
    float* bqkv = (float*)(wpack + 3538944);
    bf16* ctx = (bf16*)d_out;                 // borrow d_out (dead before LN)

    cvt_kernel<<<14018, 256, 0, stream>>>(hidden, ce, cc, vm, Wd, Wc, Wq, Wk, Wv, Wo,
                                          bq, bk, bv, hbf, hcol, wpack, bqkv);

    dim3 g6(M_ / 256, 6);
    dim3 g18(M_ / 256, 18);
    gemm_bt<0><<<g6, 512, 0, stream>>>(hbf, hcol, Wd_b, Wc_b, bd, bc, nullptr, hbuf, 2 * H_, H_);
    gemm_bt<1><<<g18, 512, 0, stream>>>(hbuf, hbuf, Wq_b, Wq_b, bqkv, nullptr, nullptr, qkv, H_, 3 * H_);
    attn_kernel<<<3072, 256, 0, stream>>>(qb, kb, vb, ctx);
    gemm_bt<2><<<g6, 512, 0, stream>>>(ctx, ctx, Wo_b, Wo_b, bo, nullptr, hbuf, hbuf, H_, H_);
    ln_kernel<<<M_ / 4, 256, 0, stream>>>(hbuf, lng, lnb, (float*)d_out);
}

// Round 5
// 370.839 us; speedup vs baseline: 1.7375x; 1.7375x over previous
//
#include <hip/hip_runtime.h>
#include <hip/hip_bf16.h>
#include <math.h>
#include <stdint.h>

#define B_    32
#define S_    512
#define H_    768
#define NH_   12
#define HD_   64
#define NCOL_ 32
#define M_    (B_*S_)   // 16384

typedef __bf16 bf16;
typedef __bf16 bf16x8 __attribute__((ext_vector_type(8)));
typedef __bf16 bf16x4 __attribute__((ext_vector_type(4)));
typedef float  f32x4  __attribute__((ext_vector_type(4)));

// ---------------------------------------------------------------------------
// async global->LDS 16B copy (global_load_lds_dwordx4)
// ---------------------------------------------------------------------------
__device__ __forceinline__ void async_load16(const void* g, void* l) {
    __builtin_amdgcn_global_load_lds(
        (__attribute__((address_space(1))) unsigned int*)g,
        (__attribute__((address_space(3))) unsigned int*)l, 16, 0, 0);
}

// fp32 -> bf16x8 converting load (32B in)
__device__ __forceinline__ bf16x8 cvt8(const float* p) {
    const float4* fp = (const float4*)p;
    float4 x = fp[0], y = fp[1];
    bf16x8 r;
    r[0] = (bf16)x.x; r[1] = (bf16)x.y; r[2] = (bf16)x.z; r[3] = (bf16)x.w;
    r[4] = (bf16)y.x; r[5] = (bf16)y.y; r[6] = (bf16)y.z; r[7] = (bf16)y.w;
    return r;
}

// ---------------------------------------------------------------------------
// fused convert: hidden->hbf, gather->hcol, weights->wpack, qkv bias pack
// ---------------------------------------------------------------------------
__global__ __launch_bounds__(256) void cvt_kernel(
    const float* __restrict__ hidden, const float* __restrict__ ce,
    const int* __restrict__ cc, const int* __restrict__ vm,
    const float* __restrict__ Wd, const float* __restrict__ Wc,
    const float* __restrict__ Wq, const float* __restrict__ Wk,
    const float* __restrict__ Wv, const float* __restrict__ Wo,
    const float* __restrict__ bq, const float* __restrict__ bk,
    const float* __restrict__ bv,
    bf16* __restrict__ hbf, bf16* __restrict__ hcol,
    bf16* __restrict__ wpack, float* __restrict__ bqkv)
{
    int blk = blockIdx.x;
    if (blk < 6144) {
        int id = blk * 256 + threadIdx.x;
        int row = id / 96, c = id - row * 96;
        *(bf16x8*)&hbf[(long)row * H_ + c * 8] = cvt8(hidden + (long)row * H_ + c * 8);
    } else if (blk < 12288) {
        int id = (blk - 6144) * 256 + threadIdx.x;
        int row = id / 96, c = id - row * 96;
        int b = row >> 9;
        int m = vm[row];
        bf16x8 val;
#pragma unroll
        for (int i = 0; i < 8; i++) val[i] = (bf16)0.0f;
        if (m > 0) {
            int col = m - 1;
            if (cc[b * NCOL_ + col] == 1)
                val = cvt8(ce + ((long)(b * NCOL_ + col)) * H_ + c * 8);
        }
        *(bf16x8*)&hcol[(long)row * H_ + c * 8] = val;
    } else {
        int id = (blk - 12288) * 256 + threadIdx.x;
        if (id < 442368) {
            const float* src;
            int r = id;
            if      (r < 73728)  { src = Wd; }
            else if (r < 147456) { src = Wc; r -= 73728; }
            else if (r < 221184) { src = Wq; r -= 147456; }
            else if (r < 294912) { src = Wk; r -= 221184; }
            else if (r < 368640) { src = Wv; r -= 294912; }
            else                 { src = Wo; r -= 368640; }
            *(bf16x8*)&wpack[(long)id * 8] = cvt8(src + (long)r * 8);
        } else if (id < 442656) {
            int j0 = (id - 442368) * 8;
#pragma unroll
            for (int i = 0; i < 8; i++) {
                int j = j0 + i;
                float v = (j < 768) ? bq[j] : (j < 1536) ? bk[j - 768] : bv[j - 1536];
                bqkv[j] = v;
            }
        }
    }
}

// ---------------------------------------------------------------------------
// GEMM C[m,n] = sum_k A[m,k]*Bw[n,k]  (+ epilogue per MODE), bf16, lda=ldb=768
//
// BM=128 BN=128 BK=32, 256 threads = 4 waves (2x2 bands, 64x64/wave).
// TRIPLE-buffered LDS at 48KB total -> 3 BLOCKS/CU, and grids are exact
// multiples of the 768-block residency capacity: GEMM0/2 (128,6)=768 = one
// full wave (perfect balance; round-2's (64,6)=384 left half the CUs with
// a single block while the 2-block CUs were the critical path). QKV
// (128,18)=2304 = exactly 3 waves.
//
// Pipeline = round-2's verified schedule (best measured: 373us total):
// counted vmcnt(4): stage(t+2) issued in iter t, drains at end of iter t+1;
// ONE barrier per K-tile; frag reads at top of iter; 2-bit XOR chunk swizzle
// via pre-swizzled global source + swizzled ds_read (conflict-free).
// NOTE (round-4 lesson): at 64x64/wave the combined VGPR+AGPR live set is
// ~124 — fragment double-buffering spills to scratch (WRITE_SIZE 4x). Do
// not add persistent register state to this loop.
//
// MODE 0: gelu(acc + bias1 + bias2) -> [M,768] bf16
// MODE 1: acc + bias1 -> qkv: Q,K sections [B,NH,S,HD]; V section [B,NH,HD,S]
// MODE 2: acc + bias1 + resid -> [M,768] bf16 (in-place ok)
// ---------------------------------------------------------------------------
template<int MODE>
__global__ __launch_bounds__(256, 3) void gemm_bt(
    const bf16* __restrict__ A0, const bf16* __restrict__ A1,
    const bf16* __restrict__ B0, const bf16* __restrict__ B1,
    const float* __restrict__ bias1, const float* __restrict__ bias2,
    const bf16* __restrict__ resid, bf16* __restrict__ out,
    int K, int KSPLIT)
{
    __shared__ __align__(16) bf16 SA[3][128 * 32];   // 3 x 8KB
    __shared__ __align__(16) bf16 SB[3][128 * 32];   // 3 x 8KB

    const int tid  = threadIdx.x;
    const int lane = tid & 63;
    const int wave = tid >> 6;
    const int wr   = wave >> 1;          // 0..1: 64-row band of A
    const int wc   = wave & 1;           // 0..1: 64-col band of B
    const int quad = lane >> 4;
    const int ln16 = lane & 15;
    const int m0   = blockIdx.x * 128;
    const int n0   = blockIdx.y * 128;

    // staging geometry: 16B chunks, 4 chunks per 32-elem row. Physical chunk
    // p in row r holds LOGICAL chunk p ^ ((r>>1)&3) -> pre-swizzle the global
    // source column so the LDS dest stays linear (global_load_lds constraint).
    int arow[2], acol[2];
#pragma unroll
    for (int q = 0; q < 2; q++) {
        int l = q * 256 + tid;
        int row = l >> 2;
        arow[q] = row;
        acol[q] = ((l & 3) ^ ((row >> 1) & 3)) * 8;
    }

    auto stage = [&](int kt, int bsel) {
        int kk = kt * 32;
        const bf16* ag = (kk < KSPLIT) ? A0 + kk : A1 + (kk - KSPLIT);
        const bf16* bg = (kk < KSPLIT) ? B0 + kk : B1 + (kk - KSPLIT);
        async_load16(ag + (long)(m0 + arow[0]) * H_ + acol[0], &SA[bsel][tid * 8]);
        async_load16(ag + (long)(m0 + arow[1]) * H_ + acol[1], &SA[bsel][2048 + tid * 8]);
        async_load16(bg + (long)(n0 + arow[0]) * H_ + acol[0], &SB[bsel][tid * 8]);
        async_load16(bg + (long)(n0 + arow[1]) * H_ + acol[1], &SB[bsel][2048 + tid * 8]);
    };

    f32x4 acc[4][4];
    const f32x4 zero4 = {0.f, 0.f, 0.f, 0.f};
#pragma unroll
    for (int i = 0; i < 4; i++)
#pragma unroll
        for (int j = 0; j < 4; j++) acc[i][j] = zero4;

    // fragment LDS offsets (swizzled read side): lane (quad,ln16) wants
    // logical chunk 'quad' of its row; phys = quad ^ ((row>>1)&3); for all
    // frag rows (band + i*16 + ln16) the swizzle key reduces to (ln16>>1)&3.
    const int s4 = (ln16 >> 1) & 3;
    int aoff[4], boff[4];
#pragma unroll
    for (int i = 0; i < 4; i++) {
        aoff[i] = (wr * 64 + i * 16 + ln16) * 32 + (quad ^ s4) * 8;
        boff[i] = (wc * 64 + i * 16 + ln16) * 32 + (quad ^ s4) * 8;
    }

    const int nt = K >> 5;               // 24 or 48 K-tiles

    // ---- prologue: tiles 0,1 -> buffers 0,1; wait tile 0 (4 loads in flight)
    stage(0, 0);
    stage(1, 1);
    asm volatile("s_waitcnt vmcnt(4)" ::: "memory");
    __builtin_amdgcn_sched_barrier(0);
    __builtin_amdgcn_s_barrier();

    int bs = 0;
    for (int t = 0; t < nt; ++t) {
        const int ps = (bs + 2 >= 3) ? bs - 1 : bs + 2;   // (t+2)%3

        // frag reads first (keeps ds_reads ahead of the aliasing LDS writes),
        // then issue next-next-tile stage; compiler inserts fine-grained
        // lgkmcnt between reads and dependent MFMAs (no manual drain).
        bf16x8 af[4], bfr[4];
#pragma unroll
        for (int i = 0; i < 4; i++) af[i]  = *(const bf16x8*)&SA[bs][aoff[i]];
#pragma unroll
        for (int j = 0; j < 4; j++) bfr[j] = *(const bf16x8*)&SB[bs][boff[j]];
        if (t + 2 < nt) stage(t + 2, ps);

        __builtin_amdgcn_s_setprio(1);
#pragma unroll
        for (int i = 0; i < 4; i++)
#pragma unroll
            for (int j = 0; j < 4; j++)
                acc[i][j] = __builtin_amdgcn_mfma_f32_16x16x32_bf16(af[i], bfr[j], acc[i][j], 0, 0, 0);
        __builtin_amdgcn_s_setprio(0);

        // end of K-tile: counted wait — tile t+1's 4 loads (oldest
        // outstanding) landed; tile t+2's 4, issued this iter, stay in
        // flight across the barrier.
        if (t + 2 < nt)       { asm volatile("s_waitcnt vmcnt(4)" ::: "memory"); }
        else if (t + 1 < nt)  { asm volatile("s_waitcnt vmcnt(0)" ::: "memory"); }
        __builtin_amdgcn_sched_barrier(0);
        if (t + 1 < nt) __builtin_amdgcn_s_barrier();
        bs = (bs + 1 == 3) ? 0 : bs + 1;
    }

    // ---- epilogue (identical per-wave 64x64 mapping, wr/wc in 0..1)
    const int c_r = quad * 4;
    const int c_c = ln16;

    int sec = 0;
    if (MODE == 1) sec = (n0 >= 1536) ? 2 : ((n0 >= 768) ? 1 : 0);
    bf16* dst = (MODE == 1) ? out + (long)sec * M_ * H_ : out;

#pragma unroll
    for (int j = 0; j < 4; j++) {
        const int col = n0 + wc * 64 + j * 16 + c_c;
        float bias = bias1[col];
        if (MODE == 0) bias += bias2[col];
#pragma unroll
        for (int i = 0; i < 4; i++) {
            if (MODE == 1 && sec == 2) {
                // V transposed [B,NH,HD,S]: 4 consecutive s -> one 8B store
                const int row0 = m0 + wr * 64 + i * 16 + c_r;   // 4-aligned
                int b = row0 >> 9, s = row0 & 511;
                int cs = col - 1536;
                int head = cs >> 6, d = cs & 63;
                bf16x4 pk;
#pragma unroll
                for (int r = 0; r < 4; r++) pk[r] = (bf16)(acc[i][j][r] + bias);
                *(bf16x4*)&dst[(((long)(b * NH_ + head)) * HD_ + d) * S_ + s] = pk;
            } else {
#pragma unroll
                for (int r = 0; r < 4; r++) {
                    const int row = m0 + wr * 64 + i * 16 + c_r + r;
                    float v = acc[i][j][r] + bias;
                    if (MODE == 0) {
                        v = 0.5f * v * (1.0f + erff(v * 0.70710678118654752f));
                        dst[(long)row * H_ + col] = (bf16)v;
                    } else if (MODE == 1) {
                        int b = row >> 9, s = row & 511;
                        int cs = col - sec * 768;
                        int head = cs >> 6, d = cs & 63;
                        dst[(((long)(b * NH_ + head)) * S_ + s) * HD_ + d] = (bf16)v;
                    } else {
                        v += (float)resid[(long)row * H_ + col];
                        dst[(long)row * H_ + col] = (bf16)v;
                    }
                }
            }
        }
    }
}

// ---------------------------------------------------------------------------
// flash attention, transposed-score form (unchanged).
// ---------------------------------------------------------------------------
#define QP 72   // LDS row stride (elems): 144 B, 16B-aligned

__global__ __launch_bounds__(256) void attn_kernel(
    const bf16* __restrict__ q, const bf16* __restrict__ k,
    const bf16* __restrict__ vt, bf16* __restrict__ ctx)
{
    __shared__ __align__(16) bf16 Qs[64 * QP];
    __shared__ __align__(16) bf16 Ks[64 * QP];
    __shared__ __align__(16) bf16 Vt[64 * QP];      // V^T chunk: [d][t]
    __shared__ __align__(16) bf16 Ps[4][16 * QP];   // per-wave P: [q][t]

    const int tid  = threadIdx.x;
    const int lane = tid & 63;
    const int w    = tid >> 6;
    const int quad = lane >> 4;
    const int ln16 = lane & 15;

    const int bid = blockIdx.x;
    const int qt  = bid / 384;          // qt-major: same g -> same XCD (384%8==0)
    const int g   = bid - qt * 384;
    const int b   = g / 12;
    const int h   = g - b * 12;
    const long base = ((long)(b * NH_ + h)) * S_ * HD_;

    const int r0 = tid >> 2;            // row 0..63
    const int e0 = (tid & 3) * 16;      // col elems 0,16,32,48

    {
        const bf16* qg = q + base + (long)qt * 64 * HD_;
        *(uint4*)&Qs[r0 * QP + e0]     = *(const uint4*)&qg[r0 * HD_ + e0];
        *(uint4*)&Qs[r0 * QP + e0 + 8] = *(const uint4*)&qg[r0 * HD_ + e0 + 8];
    }
    const bf16* kg = k  + base;
    const bf16* vg = vt + base;
    uint4 kr0 = *(const uint4*)&kg[r0 * HD_ + e0];
    uint4 kr1 = *(const uint4*)&kg[r0 * HD_ + e0 + 8];
    uint4 vr0 = *(const uint4*)&vg[(long)r0 * S_ + e0];
    uint4 vr1 = *(const uint4*)&vg[(long)r0 * S_ + e0 + 8];
    __syncthreads();

    const bf16x8 bq0 = *(const bf16x8*)&Qs[(w * 16 + ln16) * QP + quad * 8];
    const bf16x8 bq1 = *(const bf16x8*)&Qs[(w * 16 + ln16) * QP + 32 + quad * 8];

    f32x4 O[4];
    const f32x4 zero4 = {0.f, 0.f, 0.f, 0.f};
#pragma unroll
    for (int t = 0; t < 4; t++) O[t] = zero4;
    float mo = -1e30f, l = 0.f;

    for (int kc = 0; kc < 8; kc++) {
        __syncthreads();
        *(uint4*)&Ks[r0 * QP + e0]     = kr0;
        *(uint4*)&Ks[r0 * QP + e0 + 8] = kr1;
        *(uint4*)&Vt[r0 * QP + e0]     = vr0;
        *(uint4*)&Vt[r0 * QP + e0 + 8] = vr1;
        {
            int kcn = (kc < 7) ? kc + 1 : 7;
            kr0 = *(const uint4*)&kg[(long)kcn * 64 * HD_ + r0 * HD_ + e0];
            kr1 = *(const uint4*)&kg[(long)kcn * 64 * HD_ + r0 * HD_ + e0 + 8];
            vr0 = *(const uint4*)&vg[(long)r0 * S_ + kcn * 64 + e0];
            vr1 = *(const uint4*)&vg[(long)r0 * S_ + kcn * 64 + e0 + 8];
        }
        __syncthreads();

        f32x4 sc[4];
#pragma unroll
        for (int i = 0; i < 4; i++) {
            bf16x8 a0 = *(const bf16x8*)&Ks[(i * 16 + ln16) * QP + quad * 8];
            bf16x8 a1 = *(const bf16x8*)&Ks[(i * 16 + ln16) * QP + 32 + quad * 8];
            sc[i] = zero4;
            sc[i] = __builtin_amdgcn_mfma_f32_16x16x32_bf16(a0, bq0, sc[i], 0, 0, 0);
            sc[i] = __builtin_amdgcn_mfma_f32_16x16x32_bf16(a1, bq1, sc[i], 0, 0, 0);
        }

        float cm = -1e30f;
#pragma unroll
        for (int i = 0; i < 4; i++)
#pragma unroll
            for (int r = 0; r < 4; r++) {
                float s = sc[i][r] * 0.125f;
                sc[i][r] = s;
                cm = fmaxf(cm, s);
            }
        cm = fmaxf(cm, __shfl_xor(cm, 16));
        cm = fmaxf(cm, __shfl_xor(cm, 32));
        float mn = fmaxf(mo, cm);
        float alpha = __expf(mo - mn);
        float rs = 0.f;
#pragma unroll
        for (int i = 0; i < 4; i++) {
            bf16x4 pk;
#pragma unroll
            for (int r = 0; r < 4; r++) {
                float p = __expf(sc[i][r] - mn);
                rs += p;
                pk[r] = (bf16)p;
            }
            *(bf16x4*)&Ps[w][ln16 * QP + i * 16 + quad * 4] = pk;
        }
        rs += __shfl_xor(rs, 16);
        rs += __shfl_xor(rs, 32);
        l  = l * alpha + rs;
        mo = mn;
#pragma unroll
        for (int t = 0; t < 4; t++)
#pragma unroll
            for (int r = 0; r < 4; r++) O[t][r] *= alpha;

        bf16x8 bp0 = *(const bf16x8*)&Ps[w][ln16 * QP + quad * 8];
        bf16x8 bp1 = *(const bf16x8*)&Ps[w][ln16 * QP + 32 + quad * 8];
#pragma unroll
        for (int dt = 0; dt < 4; dt++) {
            bf16x8 a0 = *(const bf16x8*)&Vt[(dt * 16 + ln16) * QP + quad * 8];
            bf16x8 a1 = *(const bf16x8*)&Vt[(dt * 16 + ln16) * QP + 32 + quad * 8];
            O[dt] = __builtin_amdgcn_mfma_f32_16x16x32_bf16(a0, bp0, O[dt], 0, 0, 0);
            O[dt] = __builtin_amdgcn_mfma_f32_16x16x32_bf16(a1, bp1, O[dt], 0, 0, 0);
        }
    }

    {
        float inv = 1.0f / l;
#pragma unroll
        for (int dt = 0; dt < 4; dt++) {
            bf16x4 ov;
#pragma unroll
            for (int r = 0; r < 4; r++) ov[r] = (bf16)(O[dt][r] * inv);
            *(bf16x4*)&Qs[(w * 16 + ln16) * QP + dt * 16 + quad * 4] = ov;
        }
    }
    __syncthreads();
    {
        uint4 o0 = *(const uint4*)&Qs[r0 * QP + e0];
        uint4 o1 = *(const uint4*)&Qs[r0 * QP + e0 + 8];
        bf16* cg = ctx + ((long)(b * S_ + qt * 64 + r0)) * H_ + h * HD_;
        *(uint4*)&cg[e0]     = o0;
        *(uint4*)&cg[e0 + 8] = o1;
    }
}

// ---------------------------------------------------------------------------
// layernorm: one wave per row; bf16 in, fp32 out
// ---------------------------------------------------------------------------
__global__ __launch_bounds__(256) void ln_kernel(
    const bf16* __restrict__ y, const float* __restrict__ g,
    const float* __restrict__ be, float* __restrict__ out)
{
    const int lane = threadIdx.x & 63;
    const int w    = threadIdx.x >> 6;
    const long row = (long)blockIdx.x * 4 + w;
    const bf16* yr = y + row * H_;

    float x[12];
    float sum = 0.f, ss = 0.f;
#pragma unroll
    for (int j = 0; j < 12; j++) {
        x[j] = (float)yr[j * 64 + lane];
        sum += x[j];
        ss  += x[j] * x[j];
    }
#pragma unroll
    for (int m = 1; m < 64; m <<= 1) {
        sum += __shfl_xor(sum, m);
        ss  += __shfl_xor(ss, m);
    }
    const float mu  = sum * (1.0f / 768.0f);
    float var = ss * (1.0f / 768.0f) - mu * mu;
    const float rs = rsqrtf(fmaxf(var, 0.f) + 1e-12f);
#pragma unroll
    for (int j = 0; j < 12; j++) {
        int c = j * 64 + lane;
        out[row * H_ + c] = (x[j] - mu) * rs * g[c] + be[c];
    }
}

// ---------------------------------------------------------------------------
extern "C" void kernel_launch(void* const* d_in, const int* in_sizes, int n_in,
                              void* d_out, int out_size, void* d_ws, size_t ws_size,
                              hipStream_t stream)
{
    const float* hidden = (const float*)d_in[0];
    const float* ce     = (const float*)d_in[1];
    const int*   cc     = (const int*)d_in[2];
    const int*   vm     = (const int*)d_in[3];
    const float* Wd     = (const float*)d_in[4];
    const float* bd     = (const float*)d_in[5];
    const float* Wc     = (const float*)d_in[6];
    const float* bc     = (const float*)d_in[7];
    const float* Wq     = (const float*)d_in[8];
    const float* bq     = (const float*)d_in[9];
    const float* Wk     = (const float*)d_in[10];
    const float* bk     = (const float*)d_in[11];
    const float* Wv     = (const float*)d_in[12];
    const float* bv     = (const float*)d_in[13];
    const float* Wo     = (const float*)d_in[14];
    const float* bo     = (const float*)d_in[15];
    const float* lng    = (const float*)d_in[16];
    const float* lnb    = (const float*)d_in[17];

    // ---- workspace layout (bf16 elems; total ~102.8 MB) ----
    const long NE = (long)M_ * H_;
    bf16* ws   = (bf16*)d_ws;
    bf16* hbuf = ws;                          // gelu out / resid / y
    bf16* qkv  = ws + NE;                     // qb,kb,vb contiguous
    bf16* hbf  = qkv;                         // hbf over qb (dead before QKV writes)
    bf16* hcol = qkv + NE;                    // hcol over kb
    bf16* qb   = qkv;
    bf16* kb   = qkv + NE;
    bf16* vb   = qkv + 2 * NE;                // V^T layout [B,NH,HD,S]
    bf16* wpack = ws + 4 * NE;
    const bf16* Wd_b  = wpack;
    const bf16* Wc_b  = wpack + 589824;
    const bf16* Wq_b  = wpack + 1179648;
    const bf16* Wk_b  = wpack + 1769472;
    const bf16* Wv_b  = wpack + 2359296;
    const bf16* Wo_b  = wpack + 2949120;
    float* bqkv = (float*)(wpack + 3538944);
    bf16* ctx = (bf16*)d_out;                 // borrow d_out (dead before LN)

    cvt_kernel<<<14018, 256, 0, stream>>>(hidden, ce, cc, vm, Wd, Wc, Wq, Wk, Wv, Wo,
                                          bq, bk, bv, hbf, hcol, wpack, bqkv);

    dim3 g6(M_ / 128, 6);
    dim3 g18(M_ / 128, 18);
    gemm_bt<0><<<g6, 256, 0, stream>>>(hbf, hcol, Wd_b, Wc_b, bd, bc, nullptr, hbuf, 2 * H_, H_);
    gemm_bt<1><<<g18, 256, 0, stream>>>(hbuf, hbuf, Wq_b, Wq_b, bqkv, nullptr, nullptr, qkv, H_, 3 * H_);
    attn_kernel<<<3072, 256, 0, stream>>>(qb, kb, vb, ctx);
    gemm_bt<2><<<g6, 256, 0, stream>>>(ctx, ctx, Wo_b, Wo_b, bo, nullptr, hbuf, hbuf, H_, H_);
    ln_kernel<<<M_ / 4, 256, 0, stream>>>(hbuf, lng, lnb, (float*)d_out);
}

// Round 6
// 362.798 us; speedup vs baseline: 1.7760x; 1.0222x over previous
//
#include <hip/hip_runtime.h>
#include <hip/hip_bf16.h>
#include <math.h>
#include <stdint.h>

#define B_    32
#define S_    512
#define H_    768
#define NH_   12
#define HD_   64
#define NCOL_ 32
#define M_    (B_*S_)   // 16384

typedef __bf16 bf16;
typedef __bf16 bf16x8 __attribute__((ext_vector_type(8)));
typedef __bf16 bf16x4 __attribute__((ext_vector_type(4)));
typedef float  f32x4  __attribute__((ext_vector_type(4)));

// ---------------------------------------------------------------------------
// async global->LDS 16B copy (global_load_lds_dwordx4)
// ---------------------------------------------------------------------------
__device__ __forceinline__ void async_load16(const void* g, void* l) {
    __builtin_amdgcn_global_load_lds(
        (__attribute__((address_space(1))) unsigned int*)g,
        (__attribute__((address_space(3))) unsigned int*)l, 16, 0, 0);
}

// fp32 -> bf16x8 converting load (32B in)
__device__ __forceinline__ bf16x8 cvt8(const float* p) {
    const float4* fp = (const float4*)p;
    float4 x = fp[0], y = fp[1];
    bf16x8 r;
    r[0] = (bf16)x.x; r[1] = (bf16)x.y; r[2] = (bf16)x.z; r[3] = (bf16)x.w;
    r[4] = (bf16)y.x; r[5] = (bf16)y.y; r[6] = (bf16)y.z; r[7] = (bf16)y.w;
    return r;
}

// ---------------------------------------------------------------------------
// fused convert: hidden->hbf, gather->hcol, weights->wpack, qkv bias pack
// ---------------------------------------------------------------------------
__global__ __launch_bounds__(256) void cvt_kernel(
    const float* __restrict__ hidden, const float* __restrict__ ce,
    const int* __restrict__ cc, const int* __restrict__ vm,
    const float* __restrict__ Wd, const float* __restrict__ Wc,
    const float* __restrict__ Wq, const float* __restrict__ Wk,
    const float* __restrict__ Wv, const float* __restrict__ Wo,
    const float* __restrict__ bq, const float* __restrict__ bk,
    const float* __restrict__ bv,
    bf16* __restrict__ hbf, bf16* __restrict__ hcol,
    bf16* __restrict__ wpack, float* __restrict__ bqkv)
{
    int blk = blockIdx.x;
    if (blk < 6144) {
        int id = blk * 256 + threadIdx.x;
        int row = id / 96, c = id - row * 96;
        *(bf16x8*)&hbf[(long)row * H_ + c * 8] = cvt8(hidden + (long)row * H_ + c * 8);
    } else if (blk < 12288) {
        int id = (blk - 6144) * 256 + threadIdx.x;
        int row = id / 96, c = id - row * 96;
        int b = row >> 9;
        int m = vm[row];
        bf16x8 val;
#pragma unroll
        for (int i = 0; i < 8; i++) val[i] = (bf16)0.0f;
        if (m > 0) {
            int col = m - 1;
            if (cc[b * NCOL_ + col] == 1)
                val = cvt8(ce + ((long)(b * NCOL_ + col)) * H_ + c * 8);
        }
        *(bf16x8*)&hcol[(long)row * H_ + c * 8] = val;
    } else {
        int id = (blk - 12288) * 256 + threadIdx.x;
        if (id < 442368) {
            const float* src;
            int r = id;
            if      (r < 73728)  { src = Wd; }
            else if (r < 147456) { src = Wc; r -= 73728; }
            else if (r < 221184) { src = Wq; r -= 147456; }
            else if (r < 294912) { src = Wk; r -= 221184; }
            else if (r < 368640) { src = Wv; r -= 294912; }
            else                 { src = Wo; r -= 368640; }
            *(bf16x8*)&wpack[(long)id * 8] = cvt8(src + (long)r * 8);
        } else if (id < 442656) {
            int j0 = (id - 442368) * 8;
#pragma unroll
            for (int i = 0; i < 8; i++) {
                int j = j0 + i;
                float v = (j < 768) ? bq[j] : (j < 1536) ? bk[j - 768] : bv[j - 1536];
                bqkv[j] = v;
            }
        }
    }
}

// ---------------------------------------------------------------------------
// QKV GEMM: C[m,n] = sum_k A[m,k]*W[n,k] + bias, n in [0,2304).
// BM=256 BN=128 BK=32, 512 threads = 8 waves (4x2, 64x64/wave). Round-2's
// verified loop (measured 83us): triple-buffered 72KB LDS (2 blocks/CU),
// counted vmcnt(3), ONE barrier/K-tile, 2-bit XOR chunk swizzle.
//
// NEW epilogue: stage each wave's 64x64 C-tile through LDS (stride-72 rows,
// 16B aligned; reuses the staging LDS, dead after the loop), then write
// fully-coalesced 128B runs. Removes the 2B/8B partial-line stores that
// forced read-for-ownership (round-5 counters: FETCH 50.8MB vs 27.4 logical
// = +24MB = V section; WRITE 102 vs 72 logical).
// Q,K sections -> [B,NH,S,HD]; V section -> [B,NH,HD,S] (V^T via transposed
// LDS placement; write loop identical shape).
// ---------------------------------------------------------------------------
__global__ __launch_bounds__(512, 4) void gemm_qkv(
    const bf16* __restrict__ A, const bf16* __restrict__ Bw,
    const float* __restrict__ bias, bf16* __restrict__ out)
{
    // 72KB: SA = LB[0 .. 3*8192), SB = LB[24576 .. +3*4096).
    // Epilogue scratch: 8 waves x 64x72 elems = 36864 elems (exact fit).
    __shared__ __align__(16) bf16 LB[36864];

    const int tid  = threadIdx.x;
    const int lane = tid & 63;
    const int wave = tid >> 6;
    const int wr   = wave >> 1;          // 0..3: 64-row band of A
    const int wc   = wave & 1;           // 0..1: 64-col band of B
    const int quad = lane >> 4;
    const int ln16 = lane & 15;
    const int m0   = blockIdx.x * 256;
    const int n0   = blockIdx.y * 128;

    int arow[2], acol[2];
#pragma unroll
    for (int q = 0; q < 2; q++) {
        int l = q * 512 + tid;
        int row = l >> 2;
        arow[q] = row;
        acol[q] = ((l & 3) ^ ((row >> 1) & 3)) * 8;
    }
    const int brow = tid >> 2;
    const int bcol = ((tid & 3) ^ ((brow >> 1) & 3)) * 8;

    auto stage = [&](int kt, int bsel) {
        int kk = kt * 32;
        const bf16* ag = A + kk;
        const bf16* bg = Bw + kk;
        bf16* SAb = &LB[bsel * 8192];
        bf16* SBb = &LB[24576 + bsel * 4096];
        async_load16(ag + (long)(m0 + arow[0]) * H_ + acol[0], SAb + tid * 8);
        async_load16(ag + (long)(m0 + arow[1]) * H_ + acol[1], SAb + 4096 + tid * 8);
        async_load16(bg + (long)(n0 + brow)    * H_ + bcol,    SBb + tid * 8);
    };

    f32x4 acc[4][4];
    const f32x4 zero4 = {0.f, 0.f, 0.f, 0.f};
#pragma unroll
    for (int i = 0; i < 4; i++)
#pragma unroll
        for (int j = 0; j < 4; j++) acc[i][j] = zero4;

    const int s4 = (ln16 >> 1) & 3;
    int aoff[4], boff[4];
#pragma unroll
    for (int i = 0; i < 4; i++) {
        aoff[i] = (wr * 64 + i * 16 + ln16) * 32 + (quad ^ s4) * 8;
        boff[i] = (wc * 64 + i * 16 + ln16) * 32 + (quad ^ s4) * 8;
    }

    const int nt = 24;                    // K = 768

    stage(0, 0);
    stage(1, 1);
    asm volatile("s_waitcnt vmcnt(3)" ::: "memory");
    __builtin_amdgcn_sched_barrier(0);
    __builtin_amdgcn_s_barrier();

    int bs = 0;
    for (int t = 0; t < nt; ++t) {
        const int ps = (bs + 2 >= 3) ? bs - 1 : bs + 2;   // (t+2)%3

        bf16x8 af[4], bfr[4];
#pragma unroll
        for (int i = 0; i < 4; i++) af[i]  = *(const bf16x8*)&LB[bs * 8192 + aoff[i]];
#pragma unroll
        for (int j = 0; j < 4; j++) bfr[j] = *(const bf16x8*)&LB[24576 + bs * 4096 + boff[j]];
        if (t + 2 < nt) stage(t + 2, ps);

        __builtin_amdgcn_s_setprio(1);
#pragma unroll
        for (int i = 0; i < 4; i++)
#pragma unroll
            for (int j = 0; j < 4; j++)
                acc[i][j] = __builtin_amdgcn_mfma_f32_16x16x32_bf16(af[i], bfr[j], acc[i][j], 0, 0, 0);
        __builtin_amdgcn_s_setprio(0);

        if (t + 2 < nt)       { asm volatile("s_waitcnt vmcnt(3)" ::: "memory"); }
        else if (t + 1 < nt)  { asm volatile("s_waitcnt vmcnt(0)" ::: "memory"); }
        __builtin_amdgcn_sched_barrier(0);
        if (t + 1 < nt) __builtin_amdgcn_s_barrier();
        bs = (bs + 1 == 3) ? 0 : bs + 1;
    }

    // ---- epilogue: LDS-pack then coalesced 128B writes ----
    __syncthreads();                       // all waves done reading SA/SB
    bf16* scr = &LB[wave * 4608];          // 64 x 72 elems per wave

    const int cs0  = n0 + wc * 64;         // 64-aligned -> whole band = one head
    const int sec  = (cs0 >= 1536) ? 2 : ((cs0 >= 768) ? 1 : 0);
    const int head = (cs0 - sec * 768) >> 6;
    bf16* dst = out + (long)sec * M_ * H_;

#pragma unroll
    for (int j = 0; j < 4; j++) {
        const int d_loc = j * 16 + ln16;
        const float bj = bias[cs0 + d_loc];
#pragma unroll
        for (int i = 0; i < 4; i++) {
#pragma unroll
            for (int r = 0; r < 4; r++) {
                const int s_loc = i * 16 + quad * 4 + r;
                const float v = acc[i][j][r] + bj;
                scr[(sec == 2) ? (d_loc * 72 + s_loc) : (s_loc * 72 + d_loc)] = (bf16)v;
            }
        }
    }
    asm volatile("s_waitcnt lgkmcnt(0)" ::: "memory");
    __builtin_amdgcn_sched_barrier(0);

    const int g8 = lane >> 3;              // 0..7
    const int o8 = (lane & 7) * 8;         // 0..56
    if (sec < 2) {
        // [B,NH,S,HD]: 8-lane group writes one row's 128B; 8 rows per it-step
#pragma unroll
        for (int it = 0; it < 8; it++) {
            const int s_loc = it * 8 + g8;
            const int row_s = m0 + wr * 64 + s_loc;
            const int b = row_s >> 9, s = row_s & 511;
            *(bf16x8*)&dst[(((long)(b * NH_ + head)) * S_ + s) * HD_ + o8] =
                *(const bf16x8*)&scr[s_loc * 72 + o8];
        }
    } else {
        // V^T [B,NH,HD,S]: 64-row window is 64-aligned -> single b, s_base
        const int row0 = m0 + wr * 64;
        const int b = row0 >> 9, sb = row0 & 511;
#pragma unroll
        for (int it = 0; it < 8; it++) {
            const int d_loc = it * 8 + g8;
            *(bf16x8*)&dst[(((long)(b * NH_ + head)) * HD_ + d_loc) * S_ + sb + o8] =
                *(const bf16x8*)&scr[d_loc * 72 + o8];
        }
    }
}

// ---------------------------------------------------------------------------
// GEMM C[m,n] = sum_k A[m,k]*Bw[n,k]  (+ epilogue per MODE), bf16, lda=ldb=768
// BM=128 BN=128 BK=32, 256 threads = 4 waves (2x2, 64x64/wave). Triple-buffer
// 48KB -> 3 blocks/CU; grids (128,6)=768 = exact residency multiple.
// Round-5 verified code, used for MODE 0 and 2 only.
// ---------------------------------------------------------------------------
template<int MODE>
__global__ __launch_bounds__(256, 3) void gemm_bt(
    const bf16* __restrict__ A0, const bf16* __restrict__ A1,
    const bf16* __restrict__ B0, const bf16* __restrict__ B1,
    const float* __restrict__ bias1, const float* __restrict__ bias2,
    const bf16* __restrict__ resid, bf16* __restrict__ out,
    int K, int KSPLIT)
{
    __shared__ __align__(16) bf16 SA[3][128 * 32];   // 3 x 8KB
    __shared__ __align__(16) bf16 SB[3][128 * 32];   // 3 x 8KB

    const int tid  = threadIdx.x;
    const int lane = tid & 63;
    const int wave = tid >> 6;
    const int wr   = wave >> 1;
    const int wc   = wave & 1;
    const int quad = lane >> 4;
    const int ln16 = lane & 15;
    const int m0   = blockIdx.x * 128;
    const int n0   = blockIdx.y * 128;

    int arow[2], acol[2];
#pragma unroll
    for (int q = 0; q < 2; q++) {
        int l = q * 256 + tid;
        int row = l >> 2;
        arow[q] = row;
        acol[q] = ((l & 3) ^ ((row >> 1) & 3)) * 8;
    }

    auto stage = [&](int kt, int bsel) {
        int kk = kt * 32;
        const bf16* ag = (kk < KSPLIT) ? A0 + kk : A1 + (kk - KSPLIT);
        const bf16* bg = (kk < KSPLIT) ? B0 + kk : B1 + (kk - KSPLIT);
        async_load16(ag + (long)(m0 + arow[0]) * H_ + acol[0], &SA[bsel][tid * 8]);
        async_load16(ag + (long)(m0 + arow[1]) * H_ + acol[1], &SA[bsel][2048 + tid * 8]);
        async_load16(bg + (long)(n0 + arow[0]) * H_ + acol[0], &SB[bsel][tid * 8]);
        async_load16(bg + (long)(n0 + arow[1]) * H_ + acol[1], &SB[bsel][2048 + tid * 8]);
    };

    f32x4 acc[4][4];
    const f32x4 zero4 = {0.f, 0.f, 0.f, 0.f};
#pragma unroll
    for (int i = 0; i < 4; i++)
#pragma unroll
        for (int j = 0; j < 4; j++) acc[i][j] = zero4;

    const int s4 = (ln16 >> 1) & 3;
    int aoff[4], boff[4];
#pragma unroll
    for (int i = 0; i < 4; i++) {
        aoff[i] = (wr * 64 + i * 16 + ln16) * 32 + (quad ^ s4) * 8;
        boff[i] = (wc * 64 + i * 16 + ln16) * 32 + (quad ^ s4) * 8;
    }

    const int nt = K >> 5;

    stage(0, 0);
    stage(1, 1);
    asm volatile("s_waitcnt vmcnt(4)" ::: "memory");
    __builtin_amdgcn_sched_barrier(0);
    __builtin_amdgcn_s_barrier();

    int bs = 0;
    for (int t = 0; t < nt; ++t) {
        const int ps = (bs + 2 >= 3) ? bs - 1 : bs + 2;

        bf16x8 af[4], bfr[4];
#pragma unroll
        for (int i = 0; i < 4; i++) af[i]  = *(const bf16x8*)&SA[bs][aoff[i]];
#pragma unroll
        for (int j = 0; j < 4; j++) bfr[j] = *(const bf16x8*)&SB[bs][boff[j]];
        if (t + 2 < nt) stage(t + 2, ps);

        __builtin_amdgcn_s_setprio(1);
#pragma unroll
        for (int i = 0; i < 4; i++)
#pragma unroll
            for (int j = 0; j < 4; j++)
                acc[i][j] = __builtin_amdgcn_mfma_f32_16x16x32_bf16(af[i], bfr[j], acc[i][j], 0, 0, 0);
        __builtin_amdgcn_s_setprio(0);

        if (t + 2 < nt)       { asm volatile("s_waitcnt vmcnt(4)" ::: "memory"); }
        else if (t + 1 < nt)  { asm volatile("s_waitcnt vmcnt(0)" ::: "memory"); }
        __builtin_amdgcn_sched_barrier(0);
        if (t + 1 < nt) __builtin_amdgcn_s_barrier();
        bs = (bs + 1 == 3) ? 0 : bs + 1;
    }

    const int c_r = quad * 4;
    const int c_c = ln16;

#pragma unroll
    for (int j = 0; j < 4; j++) {
        const int col = n0 + wc * 64 + j * 16 + c_c;
        float bias = bias1[col];
        if (MODE == 0) bias += bias2[col];
#pragma unroll
        for (int i = 0; i < 4; i++) {
#pragma unroll
            for (int r = 0; r < 4; r++) {
                const int row = m0 + wr * 64 + i * 16 + c_r + r;
                float v = acc[i][j][r] + bias;
                if (MODE == 0) {
                    v = 0.5f * v * (1.0f + erff(v * 0.70710678118654752f));
                    out[(long)row * H_ + col] = (bf16)v;
                } else {
                    v += (float)resid[(long)row * H_ + col];
                    out[(long)row * H_ + col] = (bf16)v;
                }
            }
        }
    }
}

// ---------------------------------------------------------------------------
// flash attention, transposed-score form (unchanged).
// ---------------------------------------------------------------------------
#define QP 72   // LDS row stride (elems): 144 B, 16B-aligned

__global__ __launch_bounds__(256) void attn_kernel(
    const bf16* __restrict__ q, const bf16* __restrict__ k,
    const bf16* __restrict__ vt, bf16* __restrict__ ctx)
{
    __shared__ __align__(16) bf16 Qs[64 * QP];
    __shared__ __align__(16) bf16 Ks[64 * QP];
    __shared__ __align__(16) bf16 Vt[64 * QP];      // V^T chunk: [d][t]
    __shared__ __align__(16) bf16 Ps[4][16 * QP];   // per-wave P: [q][t]

    const int tid  = threadIdx.x;
    const int lane = tid & 63;
    const int w    = tid >> 6;
    const int quad = lane >> 4;
    const int ln16 = lane & 15;

    const int bid = blockIdx.x;
    const int qt  = bid / 384;          // qt-major: same g -> same XCD (384%8==0)
    const int g   = bid - qt * 384;
    const int b   = g / 12;
    const int h   = g - b * 12;
    const long base = ((long)(b * NH_ + h)) * S_ * HD_;

    const int r0 = tid >> 2;            // row 0..63
    const int e0 = (tid & 3) * 16;      // col elems 0,16,32,48

    {
        const bf16* qg = q + base + (long)qt * 64 * HD_;
        *(uint4*)&Qs[r0 * QP + e0]     = *(const uint4*)&qg[r0 * HD_ + e0];
        *(uint4*)&Qs[r0 * QP + e0 + 8] = *(const uint4*)&qg[r0 * HD_ + e0 + 8];
    }
    const bf16* kg = k  + base;
    const bf16* vg = vt + base;
    uint4 kr0 = *(const uint4*)&kg[r0 * HD_ + e0];
    uint4 kr1 = *(const uint4*)&kg[r0 * HD_ + e0 + 8];
    uint4 vr0 = *(const uint4*)&vg[(long)r0 * S_ + e0];
    uint4 vr1 = *(const uint4*)&vg[(long)r0 * S_ + e0 + 8];
    __syncthreads();

    const bf16x8 bq0 = *(const bf16x8*)&Qs[(w * 16 + ln16) * QP + quad * 8];
    const bf16x8 bq1 = *(const bf16x8*)&Qs[(w * 16 + ln16) * QP + 32 + quad * 8];

    f32x4 O[4];
    const f32x4 zero4 = {0.f, 0.f, 0.f, 0.f};
#pragma unroll
    for (int t = 0; t < 4; t++) O[t] = zero4;
    float mo = -1e30f, l = 0.f;

    for (int kc = 0; kc < 8; kc++) {
        __syncthreads();
        *(uint4*)&Ks[r0 * QP + e0]     = kr0;
        *(uint4*)&Ks[r0 * QP + e0 + 8] = kr1;
        *(uint4*)&Vt[r0 * QP + e0]     = vr0;
        *(uint4*)&Vt[r0 * QP + e0 + 8] = vr1;
        {
            int kcn = (kc < 7) ? kc + 1 : 7;
            kr0 = *(const uint4*)&kg[(long)kcn * 64 * HD_ + r0 * HD_ + e0];
            kr1 = *(const uint4*)&kg[(long)kcn * 64 * HD_ + r0 * HD_ + e0 + 8];
            vr0 = *(const uint4*)&vg[(long)r0 * S_ + kcn * 64 + e0];
            vr1 = *(const uint4*)&vg[(long)r0 * S_ + kcn * 64 + e0 + 8];
        }
        __syncthreads();

        f32x4 sc[4];
#pragma unroll
        for (int i = 0; i < 4; i++) {
            bf16x8 a0 = *(const bf16x8*)&Ks[(i * 16 + ln16) * QP + quad * 8];
            bf16x8 a1 = *(const bf16x8*)&Ks[(i * 16 + ln16) * QP + 32 + quad * 8];
            sc[i] = zero4;
            sc[i] = __builtin_amdgcn_mfma_f32_16x16x32_bf16(a0, bq0, sc[i], 0, 0, 0);
            sc[i] = __builtin_amdgcn_mfma_f32_16x16x32_bf16(a1, bq1, sc[i], 0, 0, 0);
        }

        float cm = -1e30f;
#pragma unroll
        for (int i = 0; i < 4; i++)
#pragma unroll
            for (int r = 0; r < 4; r++) {
                float s = sc[i][r] * 0.125f;
                sc[i][r] = s;
                cm = fmaxf(cm, s);
            }
        cm = fmaxf(cm, __shfl_xor(cm, 16));
        cm = fmaxf(cm, __shfl_xor(cm, 32));
        float mn = fmaxf(mo, cm);
        float alpha = __expf(mo - mn);
        float rs = 0.f;
#pragma unroll
        for (int i = 0; i < 4; i++) {
            bf16x4 pk;
#pragma unroll
            for (int r = 0; r < 4; r++) {
                float p = __expf(sc[i][r] - mn);
                rs += p;
                pk[r] = (bf16)p;
            }
            *(bf16x4*)&Ps[w][ln16 * QP + i * 16 + quad * 4] = pk;
        }
        rs += __shfl_xor(rs, 16);
        rs += __shfl_xor(rs, 32);
        l  = l * alpha + rs;
        mo = mn;
#pragma unroll
        for (int t = 0; t < 4; t++)
#pragma unroll
            for (int r = 0; r < 4; r++) O[t][r] *= alpha;

        bf16x8 bp0 = *(const bf16x8*)&Ps[w][ln16 * QP + quad * 8];
        bf16x8 bp1 = *(const bf16x8*)&Ps[w][ln16 * QP + 32 + quad * 8];
#pragma unroll
        for (int dt = 0; dt < 4; dt++) {
            bf16x8 a0 = *(const bf16x8*)&Vt[(dt * 16 + ln16) * QP + quad * 8];
            bf16x8 a1 = *(const bf16x8*)&Vt[(dt * 16 + ln16) * QP + 32 + quad * 8];
            O[dt] = __builtin_amdgcn_mfma_f32_16x16x32_bf16(a0, bp0, O[dt], 0, 0, 0);
            O[dt] = __builtin_amdgcn_mfma_f32_16x16x32_bf16(a1, bp1, O[dt], 0, 0, 0);
        }
    }

    {
        float inv = 1.0f / l;
#pragma unroll
        for (int dt = 0; dt < 4; dt++) {
            bf16x4 ov;
#pragma unroll
            for (int r = 0; r < 4; r++) ov[r] = (bf16)(O[dt][r] * inv);
            *(bf16x4*)&Qs[(w * 16 + ln16) * QP + dt * 16 + quad * 4] = ov;
        }
    }
    __syncthreads();
    {
        uint4 o0 = *(const uint4*)&Qs[r0 * QP + e0];
        uint4 o1 = *(const uint4*)&Qs[r0 * QP + e0 + 8];
        bf16* cg = ctx + ((long)(b * S_ + qt * 64 + r0)) * H_ + h * HD_;
        *(uint4*)&cg[e0]     = o0;
        *(uint4*)&cg[e0 + 8] = o1;
    }
}

// ---------------------------------------------------------------------------
// layernorm: one wave per row; bf16 in, fp32 out
// ---------------------------------------------------------------------------
__global__ __launch_bounds__(256) void ln_kernel(
    const bf16* __restrict__ y, const float* __restrict__ g,
    const float* __restrict__ be, float* __restrict__ out)
{
    const int lane = threadIdx.x & 63;
    const int w    = threadIdx.x >> 6;
    const long row = (long)blockIdx.x * 4 + w;
    const bf16* yr = y + row * H_;

    float x[12];
    float sum = 0.f, ss = 0.f;
#pragma unroll
    for (int j = 0; j < 12; j++) {
        x[j] = (float)yr[j * 64 + lane];
        sum += x[j];
        ss  += x[j] * x[j];
    }
#pragma unroll
    for (int m = 1; m < 64; m <<= 1) {
        sum += __shfl_xor(sum, m);
        ss  += __shfl_xor(ss, m);
    }
    const float mu  = sum * (1.0f / 768.0f);
    float var = ss * (1.0f / 768.0f) - mu * mu;
    const float rs = rsqrtf(fmaxf(var, 0.f) + 1e-12f);
#pragma unroll
    for (int j = 0; j < 12; j++) {
        int c = j * 64 + lane;
        out[row * H_ + c] = (x[j] - mu) * rs * g[c] + be[c];
    }
}

// ---------------------------------------------------------------------------
extern "C" void kernel_launch(void* const* d_in, const int* in_sizes, int n_in,
                              void* d_out, int out_size, void* d_ws, size_t ws_size,
                              hipStream_t stream)
{
    const float* hidden = (const float*)d_in[0];
    const float* ce     = (const float*)d_in[1];
    const int*   cc     = (const int*)d_in[2];
    const int*   vm     = (const int*)d_in[3];
    const float* Wd     = (const float*)d_in[4];
    const float* bd     = (const float*)d_in[5];
    const float* Wc     = (const float*)d_in[6];
    const float* bc     = (const float*)d_in[7];
    const float* Wq     = (const float*)d_in[8];
    const float* bq     = (const float*)d_in[9];
    const float* Wk     = (const float*)d_in[10];
    const float* bk     = (const float*)d_in[11];
    const float* Wv     = (const float*)d_in[12];
    const float* bv     = (const float*)d_in[13];
    const float* Wo     = (const float*)d_in[14];
    const float* bo     = (const float*)d_in[15];
    const float* lng    = (const float*)d_in[16];
    const float* lnb    = (const float*)d_in[17];

    // ---- workspace layout (bf16 elems; total ~102.8 MB) ----
    const long NE = (long)M_ * H_;
    bf16* ws   = (bf16*)d_ws;
    bf16* hbuf = ws;                          // gelu out / resid / y
    bf16* qkv  = ws + NE;                     // qb,kb,vb contiguous
    bf16* hbf  = qkv;                         // hbf over qb (dead before QKV writes)
    bf16* hcol = qkv + NE;                    // hcol over kb
    bf16* qb   = qkv;
    bf16* kb   = qkv + NE;
    bf16* vb   = qkv + 2 * NE;                // V^T layout [B,NH,HD,S]
    bf16* wpack = ws + 4 * NE;
    const bf16* Wd_b  = wpack;
    const bf16* Wc_b  = wpack + 589824;
    const bf16* Wq_b  = wpack + 1179648;      // Wq,Wk,Wv contiguous: 2304x768
    const bf16* Wo_b  = wpack + 2949120;
    float* bqkv = (float*)(wpack + 3538944);
    bf16* ctx = (bf16*)d_out;                 // borrow d_out (dead before LN)

    cvt_kernel<<<14018, 256, 0, stream>>>(hidden, ce, cc, vm, Wd, Wc, Wq, Wk, Wv, Wo,
                                          bq, bk, bv, hbf, hcol, wpack, bqkv);

    dim3 g6(M_ / 128, 6);
    gemm_bt<0><<<g6, 256, 0, stream>>>(hbf, hcol, Wd_b, Wc_b, bd, bc, nullptr, hbuf, 2 * H_, H_);
    gemm_qkv<<<dim3(M_ / 256, 18), 512, 0, stream>>>(hbuf, Wq_b, bqkv, qkv);
    attn_kernel<<<3072, 256, 0, stream>>>(qb, kb, vb, ctx);
    gemm_bt<2><<<g6, 256, 0, stream>>>(ctx, ctx, Wo_b, Wo_b, bo, nullptr, hbuf, hbuf, H_, H_);
    ln_kernel<<<M_ / 4, 256, 0, stream>>>(hbuf, lng, lnb, (float*)d_out);
}